// Round 6
// baseline (348.420 us; speedup 1.0000x reference)
//
#include <hip/hip_runtime.h>
#include <math.h>

#define NHID 1024
#define NPC  225
#define NCLS 224
#define BATCH 1024
#define MAXS  64

// One block per class. Self-scan labels; per 8-sample chunk, fused dual
// matvec (bottom slice from HBM w/ NT + top Wt from L2) -> two softmax
// phases -> out[s] = p_top * p_bottom. No inter-kernel deps, X read once.
// 224 blocks ~ 1 block/CU; (512,2) allows up to 256 VGPR (no spill).
__global__ __launch_bounds__(512, 2) void hs_class(
    const float* __restrict__ X, const int* __restrict__ labels,
    const float* __restrict__ Wt, const float* __restrict__ bt,
    const float* __restrict__ Wb, const float* __restrict__ bb,
    float* __restrict__ out)
{
    __shared__ __align__(16) float sm[12288];  // in_t[1024][12] / red[4][8][232]
    __shared__ float pbuf[8];
    __shared__ int s_cnt;
    __shared__ int s_ids[MAXS];
    const int cls  = blockIdx.x;
    const int tid  = threadIdx.x;
    const int wave = tid >> 6;
    const int lane = tid & 63;

    // ---- self-scan: collect this class's samples (order-independent) ----
    if (tid == 0) s_cnt = 0;
    __syncthreads();
    for (int i = tid; i < BATCH; i += 512) {
        if (labels[i] / NPC == cls) {
            int p = atomicAdd(&s_cnt, 1);
            if (p < MAXS) s_ids[p] = i;
        }
    }
    __syncthreads();
    const int cnt = min(s_cnt, MAXS);
    if (cnt == 0) return;

    const int c0 = lane, c1 = lane + 64, c2 = lane + 128, c3 = lane + 192;
    const bool mb3 = (c3 < NPC);    // lanes 0..32
    const bool mt3 = (c3 < NCLS);   // lanes 0..31
    const int d0 = wave * 128;      // wave's d-row range
    const float* Wbr = Wb + (size_t)cls * (NHID * NPC) + (size_t)d0 * NPC;
    const float* Wtr = Wt + (size_t)d0 * NCLS;

    for (int base = 0; base < cnt; base += 8) {
        const int nt = min(8, cnt - base);

        // ---- stage up to 8 gathered X rows, transposed (stride 12) ----
        for (int idx = tid; idx < 2048; idx += 512) {
            const int j  = idx >> 8;
            const int d4 = idx & 255;
            float4 v = make_float4(0.f, 0.f, 0.f, 0.f);
            if (j < nt) v = ((const float4*)&X[(size_t)s_ids[base + j] * NHID])[d4];
            sm[(4 * d4 + 0) * 12 + j] = v.x;
            sm[(4 * d4 + 1) * 12 + j] = v.y;
            sm[(4 * d4 + 2) * 12 + j] = v.z;
            sm[(4 * d4 + 3) * 12 + j] = v.w;
        }
        __syncthreads();

        float ab[8][4], at[8][4];
#pragma unroll
        for (int j = 0; j < 8; ++j)
#pragma unroll
            for (int k = 0; k < 4; ++k) { ab[j][k] = 0.f; at[j][k] = 0.f; }

        auto ldb = [&](int r, float* o) {   // bottom slice: HBM stream, NT
            const float* p = Wbr + (size_t)r * NPC;
            o[0] = __builtin_nontemporal_load(p + c0);
            o[1] = __builtin_nontemporal_load(p + c1);
            o[2] = __builtin_nontemporal_load(p + c2);
            o[3] = mb3 ? __builtin_nontemporal_load(p + c3) : 0.f;
        };
        auto ldt = [&](int r, float* o) {   // top weights: L2-resident
            const float* p = Wtr + (size_t)r * NCLS;
            o[0] = p[c0]; o[1] = p[c1]; o[2] = p[c2];
            o[3] = mt3 ? p[c3] : 0.f;
        };
        float wb_[4][4], wt_[4][4];
        ldb(0, wb_[0]); ldb(1, wb_[1]); ldb(2, wb_[2]); ldb(3, wb_[3]);
        ldt(0, wt_[0]); ldt(1, wt_[1]); ldt(2, wt_[2]); ldt(3, wt_[3]);

#pragma unroll 4
        for (int dd = 0; dd < 128; ++dd) {
            const int slot = dd & 3;
            const float b0 = wb_[slot][0], b1 = wb_[slot][1],
                        b2 = wb_[slot][2], b3 = wb_[slot][3];
            const float t0 = wt_[slot][0], t1 = wt_[slot][1],
                        t2 = wt_[slot][2], t3 = wt_[slot][3];
            const int pf = min(dd + 4, 127);   // clamped tail re-read (cache hit)
            ldb(pf, wb_[slot]);
            ldt(pf, wt_[slot]);
            const float4 a = *(const float4*)&sm[(d0 + dd) * 12 + 0];
            const float4 b = *(const float4*)&sm[(d0 + dd) * 12 + 4];
            const float xi[8] = {a.x, a.y, a.z, a.w, b.x, b.y, b.z, b.w};
#pragma unroll
            for (int j = 0; j < 8; ++j) {
                ab[j][0] = fmaf(xi[j], b0, ab[j][0]);
                ab[j][1] = fmaf(xi[j], b1, ab[j][1]);
                ab[j][2] = fmaf(xi[j], b2, ab[j][2]);
                ab[j][3] = fmaf(xi[j], b3, ab[j][3]);
                at[j][0] = fmaf(xi[j], t0, at[j][0]);
                at[j][1] = fmaf(xi[j], t1, at[j][1]);
                at[j][2] = fmaf(xi[j], t2, at[j][2]);
                at[j][3] = fmaf(xi[j], t3, at[j][3]);
            }
        }
        __syncthreads();   // done reading staging

        float* red = sm;   // red[w][j][232], w=0..3

        // ================= phase 1: bottom softmax =================
        if (wave >= 4) {
#pragma unroll
            for (int j = 0; j < 8; ++j)
#pragma unroll
                for (int k = 0; k < 4; ++k) {
                    int c = lane + 64 * k;
                    if (c < NPC) red[((wave - 4) * 8 + j) * 232 + c] = ab[j][k];
                }
        }
        __syncthreads();
        if (wave < 4) {
#pragma unroll
            for (int j = 0; j < 8; ++j)
#pragma unroll
                for (int k = 0; k < 4; ++k) {
                    int c = lane + 64 * k;
                    if (c < NPC) red[(wave * 8 + j) * 232 + c] += ab[j][k];
                }
        }
        __syncthreads();
        {
            const int j = wave;
            if (j < nt) {
                const int s = s_ids[base + j];
                float v[4];
#pragma unroll
                for (int k = 0; k < 4; ++k) {
                    int c = lane + 64 * k;
                    v[k] = (c < NPC)
                             ? (red[(0 * 8 + j) * 232 + c] + red[(1 * 8 + j) * 232 + c] +
                                red[(2 * 8 + j) * 232 + c] + red[(3 * 8 + j) * 232 + c] +
                                bb[(size_t)cls * NPC + c])
                             : -INFINITY;
                }
                float m = fmaxf(fmaxf(v[0], v[1]), fmaxf(v[2], v[3]));
                for (int o = 32; o > 0; o >>= 1) m = fmaxf(m, __shfl_xor(m, o));
                float e = expf(v[0] - m) + expf(v[1] - m) + expf(v[2] - m) + expf(v[3] - m);
                for (int o = 32; o > 0; o >>= 1) e += __shfl_xor(e, o);
                const int pb = labels[s] % NPC;
                if (lane == (pb & 63))
                    pbuf[j] = expf(v[pb >> 6] - m) / e;
            }
        }
        __syncthreads();   // red free for phase 2; pbuf visible

        // ================= phase 2: top softmax + output =================
        if (wave >= 4) {
#pragma unroll
            for (int j = 0; j < 8; ++j)
#pragma unroll
                for (int k = 0; k < 4; ++k) {
                    int c = lane + 64 * k;
                    if (c < NCLS) red[((wave - 4) * 8 + j) * 232 + c] = at[j][k];
                }
        }
        __syncthreads();
        if (wave < 4) {
#pragma unroll
            for (int j = 0; j < 8; ++j)
#pragma unroll
                for (int k = 0; k < 4; ++k) {
                    int c = lane + 64 * k;
                    if (c < NCLS) red[(wave * 8 + j) * 232 + c] += at[j][k];
                }
        }
        __syncthreads();
        {
            const int j = wave;
            if (j < nt) {
                const int s = s_ids[base + j];
                float v[4];
#pragma unroll
                for (int k = 0; k < 4; ++k) {
                    int c = lane + 64 * k;
                    v[k] = (c < NCLS)
                             ? (red[(0 * 8 + j) * 232 + c] + red[(1 * 8 + j) * 232 + c] +
                                red[(2 * 8 + j) * 232 + c] + red[(3 * 8 + j) * 232 + c] +
                                bt[c])
                             : -INFINITY;
                }
                float m = fmaxf(fmaxf(v[0], v[1]), fmaxf(v[2], v[3]));
                for (int o = 32; o > 0; o >>= 1) m = fmaxf(m, __shfl_xor(m, o));
                float e = expf(v[0] - m) + expf(v[1] - m) + expf(v[2] - m) + expf(v[3] - m);
                for (int o = 32; o > 0; o >>= 1) e += __shfl_xor(e, o);
                // cls == labels[s]/NPC for every sample in this block
                if (lane == (cls & 63))
                    out[s] = pbuf[j] * (expf(v[cls >> 6] - m) / e);
            }
        }
        __syncthreads();   // before next chunk overwrites staging
    }
}

// ---------------------------------------------------------------------------
extern "C" void kernel_launch(void* const* d_in, const int* in_sizes, int n_in,
                              void* d_out, int out_size, void* d_ws, size_t ws_size,
                              hipStream_t stream)
{
    const float* X      = (const float*)d_in[0];
    const int*   labels = (const int*)  d_in[1];
    const float* Wt     = (const float*)d_in[2];
    const float* bt     = (const float*)d_in[3];
    const float* Wb     = (const float*)d_in[4];
    const float* bb     = (const float*)d_in[5];

    hipLaunchKernelGGL(hs_class, dim3(NCLS), dim3(512), 0, stream,
                       X, labels, Wt, bt, Wb, bb, (float*)d_out);
}

// Round 7
// 304.973 us; speedup vs baseline: 1.1425x; 1.1425x over previous
//
#include <hip/hip_runtime.h>
#include <math.h>

#define NHID 1024
#define NPC  225
#define NCLS 224
#define BATCH 1024

#define MAX_ITEMS 352
#define N_TOP     (BATCH / 8)   // 128

// ws int-offsets (written by k1's grouping block, read by k2; separate
// launches on one stream -> no device-scope atomics needed)
#define WS_NITEMS 0
#define WS_ORDER  16            // int order[1024]
#define WS_ITEMS  2048          // int items[352][4] = cls, s0, nt, pad
#define WS_PTOP   4096          // float ptop[1024]

// ---------------------------------------------------------------------------
// Grouping (runs as block N_TOP of k1, 1024 threads): histogram, scans,
// item emission, scatter. LDS aliased into caller's sm buffer.
// ---------------------------------------------------------------------------
__device__ __forceinline__ void group_samples(const int* __restrict__ labels,
                                              int* __restrict__ ws,
                                              float* __restrict__ smf, int tid)
{
    int* cnt   = (int*)smf;
    int* scan  = (int*)smf + 256;
    int* iscan = (int*)smf + 512;
    int* cur   = (int*)smf + 768;

    if (tid < 256) cnt[tid] = 0;
    __syncthreads();
    for (int i = tid; i < BATCH; i += 1024)
        atomicAdd(&cnt[labels[i] / NPC], 1);
    __syncthreads();

    int myc = 0, myi = 0;
    if (tid < 256) {
        myc = (tid < NCLS) ? cnt[tid] : 0;
        myi = (myc + 7) >> 3;
        scan[tid]  = myc;
        iscan[tid] = myi;
    }
    __syncthreads();
    for (int off = 1; off < 256; off <<= 1) {
        int a = 0, b = 0;
        if (tid < 256 && tid >= off) { a = scan[tid - off]; b = iscan[tid - off]; }
        __syncthreads();
        if (tid < 256) { scan[tid] += a; iscan[tid] += b; }
        __syncthreads();
    }
    if (tid < 256) {
        const int sbase = scan[tid]  - myc;
        const int ibase = iscan[tid] - myi;
        if (tid == 255) ws[WS_NITEMS] = iscan[255];
        cur[tid] = sbase;
        if (tid < NCLS) {
            for (int t = 0; t < myi; ++t) {
                int* it = ws + WS_ITEMS + 4 * (ibase + t);
                it[0] = tid;
                it[1] = sbase + 8 * t;
                it[2] = min(8, myc - 8 * t);
            }
        }
    }
    __syncthreads();
    for (int i = tid; i < BATCH; i += 1024) {
        int c = labels[i] / NPC;
        int p = atomicAdd(&cur[c], 1);
        ws[WS_ORDER + p] = i;
    }
}

// ---------------------------------------------------------------------------
// K1: blocks 0..127 top softmax (8 samples each), block 128 grouping.
// 1024 threads = 16 waves; wave w covers d-rows [64w, 64w+64).
// 4-deep register prefetch; 16->8 group LDS reduction; waves 0..7 finalize.
// ---------------------------------------------------------------------------
__global__ __launch_bounds__(1024, 4) void k1_top(const float* __restrict__ X,
                                                  const int* __restrict__ labels,
                                                  const float* __restrict__ Wt,
                                                  const float* __restrict__ bt,
                                                  int* __restrict__ ws)
{
    __shared__ __align__(16) float sm[14848]; // in_t[1024][12] / red[8][8][232]
    const int tid  = threadIdx.x;
    const int wave = tid >> 6;
    const int lane = tid & 63;

    if (blockIdx.x == N_TOP) {
        group_samples(labels, ws, sm, tid);
        return;
    }
    const int sbase = blockIdx.x * 8;

    // stage 8 rows transposed, j-inner lane mapping (4-way LDS banks, not 32)
    for (int idx = tid; idx < 2048; idx += 1024) {
        const int j  = idx & 7;
        const int d4 = idx >> 3;
        const float4 v = ((const float4*)&X[(size_t)(sbase + j) * NHID])[d4];
        float* p = &sm[48 * d4 + j];    // (4*d4 + r)*12 + j
        p[0] = v.x; p[12] = v.y; p[24] = v.z; p[36] = v.w;
    }
    __syncthreads();

    float acc[8][4];
#pragma unroll
    for (int j = 0; j < 8; ++j)
#pragma unroll
        for (int k = 0; k < 4; ++k) acc[j][k] = 0.f;

    const int c0 = lane, c1 = lane + 64, c2 = lane + 128, c3 = lane + 192;
    const bool m3 = (c3 < NCLS);
    const int d0 = wave * 64;
    const float* Wr = Wt + (size_t)d0 * NCLS;

    auto ldrow = [&](int r, float* o) {
        const float* p = Wr + (size_t)r * NCLS;
        o[0] = p[c0]; o[1] = p[c1]; o[2] = p[c2];
        o[3] = m3 ? p[c3] : 0.f;
    };
    float wbuf[4][4];
    ldrow(0, wbuf[0]); ldrow(1, wbuf[1]); ldrow(2, wbuf[2]); ldrow(3, wbuf[3]);

#pragma unroll 4
    for (int dd = 0; dd < 64; ++dd) {
        const int slot = dd & 3;
        const float cw0 = wbuf[slot][0], cw1 = wbuf[slot][1],
                    cw2 = wbuf[slot][2], cw3 = wbuf[slot][3];
        ldrow(min(dd + 4, 63), wbuf[slot]);   // clamped tail re-read (cache hit)
        const float4 a = *(const float4*)&sm[(d0 + dd) * 12 + 0];
        const float4 b = *(const float4*)&sm[(d0 + dd) * 12 + 4];
        const float xi[8] = {a.x, a.y, a.z, a.w, b.x, b.y, b.z, b.w};
#pragma unroll
        for (int j = 0; j < 8; ++j) {
            acc[j][0] = fmaf(xi[j], cw0, acc[j][0]);
            acc[j][1] = fmaf(xi[j], cw1, acc[j][1]);
            acc[j][2] = fmaf(xi[j], cw2, acc[j][2]);
            acc[j][3] = fmaf(xi[j], cw3, acc[j][3]);
        }
    }
    __syncthreads();   // all waves done reading staging

    float* red = sm;   // red[(g*8 + j)*232 + c], g = 0..7
    if (wave >= 8) {
#pragma unroll
        for (int j = 0; j < 8; ++j)
#pragma unroll
            for (int k = 0; k < 4; ++k) {
                int c = lane + 64 * k;
                if (c < NCLS) red[((wave - 8) * 8 + j) * 232 + c] = acc[j][k];
            }
    }
    __syncthreads();
    if (wave < 8) {
#pragma unroll
        for (int j = 0; j < 8; ++j)
#pragma unroll
            for (int k = 0; k < 4; ++k) {
                int c = lane + 64 * k;
                if (c < NCLS) red[(wave * 8 + j) * 232 + c] += acc[j][k];
            }
    }
    __syncthreads();

    if (wave < 8) {
        const int j = wave;
        const int s = sbase + j;
        float v[4];
#pragma unroll
        for (int k = 0; k < 4; ++k) {
            int c = lane + 64 * k;
            if (c < NCLS) {
                float t = bt[c];
#pragma unroll
                for (int g = 0; g < 8; ++g) t += red[(g * 8 + j) * 232 + c];
                v[k] = t;
            } else v[k] = -INFINITY;
        }
        float m = fmaxf(fmaxf(v[0], v[1]), fmaxf(v[2], v[3]));
        for (int o = 32; o > 0; o >>= 1) m = fmaxf(m, __shfl_xor(m, o));
        float e = expf(v[0] - m) + expf(v[1] - m) + expf(v[2] - m) + expf(v[3] - m);
        for (int o = 32; o > 0; o >>= 1) e += __shfl_xor(e, o);
        const int pt = labels[s] / NPC;
        if (lane == (pt & 63))
            ((float*)(ws + WS_PTOP))[s] = expf(v[pt >> 6] - m) / e;
    }
}

// ---------------------------------------------------------------------------
// K2: item-based bottom softmax + final multiply. 1024 threads = 16 waves;
// wave w covers d-rows [64w, 64w+64); NT weight stream, 4-deep prefetch.
// ---------------------------------------------------------------------------
__global__ __launch_bounds__(1024, 4) void k2_bottom(const float* __restrict__ X,
                                                     const int* __restrict__ labels,
                                                     const float* __restrict__ Wb,
                                                     const float* __restrict__ bb,
                                                     const int* __restrict__ ws,
                                                     float* __restrict__ out)
{
    __shared__ __align__(16) float sm[14848];
    const int nitems = ws[WS_NITEMS];
    if ((int)blockIdx.x >= nitems) return;
    const int* it = ws + WS_ITEMS + 4 * blockIdx.x;
    const int cls = it[0], s0 = it[1], nt = it[2];

    const int tid  = threadIdx.x;
    const int wave = tid >> 6;
    const int lane = tid & 63;

    int s_ids[8];
#pragma unroll
    for (int j = 0; j < 8; ++j)
        s_ids[j] = (j < nt) ? ws[WS_ORDER + s0 + j] : 0;

    for (int idx = tid; idx < 2048; idx += 1024) {
        const int j  = idx & 7;
        const int d4 = idx >> 3;
        float4 v = make_float4(0.f, 0.f, 0.f, 0.f);
        if (j < nt) v = ((const float4*)&X[(size_t)s_ids[j] * NHID])[d4];
        float* p = &sm[48 * d4 + j];
        p[0] = v.x; p[12] = v.y; p[24] = v.z; p[36] = v.w;
    }
    __syncthreads();

    float acc[8][4];
#pragma unroll
    for (int j = 0; j < 8; ++j)
#pragma unroll
        for (int k = 0; k < 4; ++k) acc[j][k] = 0.f;

    const int c0 = lane, c1 = lane + 64, c2 = lane + 128, c3 = lane + 192;
    const bool m3 = (c3 < NPC);
    const int d0 = wave * 64;
    const float* Wr = Wb + (size_t)cls * (NHID * NPC) + (size_t)d0 * NPC;

    auto ldrow = [&](int r, float* o) {
        const float* p = Wr + (size_t)r * NPC;
        o[0] = __builtin_nontemporal_load(p + c0);
        o[1] = __builtin_nontemporal_load(p + c1);
        o[2] = __builtin_nontemporal_load(p + c2);
        o[3] = m3 ? __builtin_nontemporal_load(p + c3) : 0.f;
    };
    float wbuf[4][4];
    ldrow(0, wbuf[0]); ldrow(1, wbuf[1]); ldrow(2, wbuf[2]); ldrow(3, wbuf[3]);

#pragma unroll 4
    for (int dd = 0; dd < 64; ++dd) {
        const int slot = dd & 3;
        const float cw0 = wbuf[slot][0], cw1 = wbuf[slot][1],
                    cw2 = wbuf[slot][2], cw3 = wbuf[slot][3];
        ldrow(min(dd + 4, 63), wbuf[slot]);
        const float4 a = *(const float4*)&sm[(d0 + dd) * 12 + 0];
        const float4 b = *(const float4*)&sm[(d0 + dd) * 12 + 4];
        const float xi[8] = {a.x, a.y, a.z, a.w, b.x, b.y, b.z, b.w};
#pragma unroll
        for (int j = 0; j < 8; ++j) {
            acc[j][0] = fmaf(xi[j], cw0, acc[j][0]);
            acc[j][1] = fmaf(xi[j], cw1, acc[j][1]);
            acc[j][2] = fmaf(xi[j], cw2, acc[j][2]);
            acc[j][3] = fmaf(xi[j], cw3, acc[j][3]);
        }
    }
    __syncthreads();

    float* red = sm;   // red[(g*8 + j)*232 + c], g = 0..7
    if (wave >= 8) {
#pragma unroll
        for (int j = 0; j < 8; ++j)
#pragma unroll
            for (int k = 0; k < 4; ++k) {
                int c = lane + 64 * k;
                if (c < NPC) red[((wave - 8) * 8 + j) * 232 + c] = acc[j][k];
            }
    }
    __syncthreads();
    if (wave < 8) {
#pragma unroll
        for (int j = 0; j < 8; ++j)
#pragma unroll
            for (int k = 0; k < 4; ++k) {
                int c = lane + 64 * k;
                if (c < NPC) red[(wave * 8 + j) * 232 + c] += acc[j][k];
            }
    }
    __syncthreads();

    if (wave < 8) {
        const int j = wave;
        if (j < nt) {
            const int s = s_ids[j];
            float v[4];
#pragma unroll
            for (int k = 0; k < 4; ++k) {
                int c = lane + 64 * k;
                if (c < NPC) {
                    float t = bb[(size_t)cls * NPC + c];
#pragma unroll
                    for (int g = 0; g < 8; ++g) t += red[(g * 8 + j) * 232 + c];
                    v[k] = t;
                } else v[k] = -INFINITY;
            }
            float m = fmaxf(fmaxf(v[0], v[1]), fmaxf(v[2], v[3]));
            for (int o = 32; o > 0; o >>= 1) m = fmaxf(m, __shfl_xor(m, o));
            float e = expf(v[0] - m) + expf(v[1] - m) + expf(v[2] - m) + expf(v[3] - m);
            for (int o = 32; o > 0; o >>= 1) e += __shfl_xor(e, o);
            const int pb = labels[s] % NPC;
            if (lane == (pb & 63)) {
                const float pt = ((const float*)(ws + WS_PTOP))[s];
                out[s] = pt * (expf(v[pb >> 6] - m) / e);
            }
        }
    }
}

// ---------------------------------------------------------------------------
extern "C" void kernel_launch(void* const* d_in, const int* in_sizes, int n_in,
                              void* d_out, int out_size, void* d_ws, size_t ws_size,
                              hipStream_t stream)
{
    const float* X      = (const float*)d_in[0];
    const int*   labels = (const int*)  d_in[1];
    const float* Wt     = (const float*)d_in[2];
    const float* bt     = (const float*)d_in[3];
    const float* Wb     = (const float*)d_in[4];
    const float* bb     = (const float*)d_in[5];

    hipLaunchKernelGGL(k1_top, dim3(N_TOP + 1), dim3(1024), 0, stream,
                       X, labels, Wt, bt, (int*)d_ws);
    hipLaunchKernelGGL(k2_bottom, dim3(MAX_ITEMS), dim3(1024), 0, stream,
                       X, labels, Wb, bb, (const int*)d_ws, (float*)d_out);
}